// Round 2
// baseline (388.085 us; speedup 1.0000x reference)
//
#include <hip/hip_runtime.h>

#define BB 8
#define SS 1024
#define HH 768
#define EE 9
#define DD 64
#define NCOL (EE * 2 * DD)  // 1152

typedef __bf16 bf16x8 __attribute__((ext_vector_type(8)));
typedef float f32x4 __attribute__((ext_vector_type(4)));

__device__ __forceinline__ unsigned short f2b(float f) {
    unsigned int x = __float_as_uint(f);
    unsigned int r = (x + 0x7fffu + ((x >> 16) & 1u)) >> 16;
    return (unsigned short)r;
}

__device__ __forceinline__ void gload_lds16(const void* g, void* l) {
    __builtin_amdgcn_global_load_lds(
        (const __attribute__((address_space(1))) void*)g,
        (__attribute__((address_space(3))) void*)l, 16, 0, 0);
}

// ---------------------------------------------------------------------------
// Kernel 0: f32 -> bf16 (RNE), vectorized.
// ---------------------------------------------------------------------------
__global__ __launch_bounds__(256) void to_bf16(const float* __restrict__ in,
                                               unsigned short* __restrict__ out,
                                               int n4) {
    int i = blockIdx.x * 256 + threadIdx.x;
    if (i >= n4) return;
    float4 v = ((const float4*)in)[i];
    ushort4 o = {f2b(v.x), f2b(v.y), f2b(v.z), f2b(v.w)};
    ((ushort4*)out)[i] = o;
}

// ---------------------------------------------------------------------------
// Kernel 1: C = A @ W^T + bias, RoPE, write q/k bf16 to ws [b*E+e][s][d].
// m97 staging (global_load_lds w=16, linear LDS, BK=32). OPERAND-SWAPPED
// MFMA: acc[nt][st] = mfma(W_frag, A_frag) so the output row index is the
// d (column) axis -> each lane holds 4 consecutive d per fragment:
//   d = nt*16 + quad*4 + reg,  s = st*16 + lr.
// Benefits: ushort4 stores (was 2B scalar), float4 bias loads, and reg-pairs
// share a RoPE half-index so sincos count halves (64 -> 32 per lane).
// Rotate-half partner (d +/- 32) is nt +/- 2, same lane & reg.
// ---------------------------------------------------------------------------
__global__ __launch_bounds__(256) void dense_rope_mfma(
    const unsigned short* __restrict__ Abf,  // [8192][768] bf16
    const unsigned short* __restrict__ Wbf,  // [1152][768] bf16
    const float* __restrict__ bias,          // [1152]
    unsigned short* __restrict__ q_ws,
    unsigned short* __restrict__ k_ws) {
    __shared__ unsigned short As[128 * 32];  // linear: gload_lds needs it
    __shared__ unsigned short Bs[128 * 32];

    const int t = threadIdx.x;
    const int lane = t & 63, wave = t >> 6;
    const int quad = lane >> 4, lr = lane & 15;
    const int wm = wave >> 1, wn = wave & 1;
    const int j0 = blockIdx.x * 128;  // x-major over N: consecutive blocks reuse A in L2
    const int m0 = blockIdx.y * 128;

    f32x4 acc[4][4] = {};  // [nt][st]

    // Staging: 128x32 bf16 tile = 8 KB = 512 x 16B chunks.
    const int srow = wave * 16 + (lane >> 2);   // + i*64
    const int sc8 = (lane & 3) * 8;

    for (int kt = 0; kt < HH / 32; ++kt) {
        const int k0 = kt * 32;
        __syncthreads();  // previous tile's LDS fully consumed
#pragma unroll
        for (int i = 0; i < 2; ++i) {
            const int row = i * 64 + srow;
            const int lb = i * 2048 + wave * 512;  // ushort offset of chunk base
            gload_lds16(&Abf[(size_t)(m0 + row) * HH + k0 + sc8], &As[lb]);
            gload_lds16(&Wbf[(size_t)(j0 + row) * HH + k0 + sc8], &Bs[lb]);
        }
        __syncthreads();  // drains vmcnt(0): staged tile visible

        bf16x8 af[4], bf[4];
#pragma unroll
        for (int nt = 0; nt < 4; ++nt)
            af[nt] = *(const bf16x8*)&Bs[(wn * 64 + nt * 16 + lr) * 32 + quad * 8];
#pragma unroll
        for (int st = 0; st < 4; ++st)
            bf[st] = *(const bf16x8*)&As[(wm * 64 + st * 16 + lr) * 32 + quad * 8];
#pragma unroll
        for (int nt = 0; nt < 4; ++nt)
#pragma unroll
            for (int st = 0; st < 4; ++st)
                acc[nt][st] = __builtin_amdgcn_mfma_f32_16x16x32_bf16(
                    af[nt], bf[st], acc[nt][st], 0, 0, 0);
    }

    // Epilogue: bias + RoPE entirely in registers, vectorized stores.
    const int gcol0 = j0 + wn * 64;       // aligned 64-col group
    const int g = gcol0 >> 6;
    const int e = g >> 1;
    unsigned short* dst = (g & 1) ? k_ws : q_ws;
    const int b_idx = m0 >> 10;           // 128 | 1024, uniform per block
    const size_t zbase = (size_t)(b_idx * EE + e) * SS;
    const float L2C = 0.4152410118609203f;  // log2(10000)/32

    float4 bb[4];
    float iv0[4], iv1[4];
#pragma unroll
    for (int nt = 0; nt < 4; ++nt) {
        bb[nt] = *(const float4*)&bias[gcol0 + nt * 16 + quad * 4];
        const int h0 = nt * 8 + quad * 2;   // = d>>1 for reg 0,1; h0+1 for reg 2,3
        iv0[nt] = exp2f(-(float)h0 * L2C);
        iv1[nt] = exp2f(-(float)(h0 + 1) * L2C);
    }
    const int s0 = (m0 & (SS - 1)) + wm * 64;
#pragma unroll
    for (int st = 0; st < 4; ++st) {
        const int s = s0 + st * 16 + lr;
        const float sf = (float)s;
        float c[4][4];
#pragma unroll
        for (int nt = 0; nt < 4; ++nt) {
            c[nt][0] = acc[nt][st][0] + bb[nt].x;
            c[nt][1] = acc[nt][st][1] + bb[nt].y;
            c[nt][2] = acc[nt][st][2] + bb[nt].z;
            c[nt][3] = acc[nt][st][3] + bb[nt].w;
        }
        unsigned short* drow = &dst[(zbase + s) * DD + quad * 4];
#pragma unroll
        for (int nt = 0; nt < 4; ++nt) {
            float sv0, cv0, sv1, cv1;
            __sincosf(sf * iv0[nt], &sv0, &cv0);
            __sincosf(sf * iv1[nt], &sv1, &cv1);
            float r0 = (nt < 2) ? -c[nt + 2][0] : c[nt - 2][0];
            float r1 = (nt < 2) ? -c[nt + 2][1] : c[nt - 2][1];
            float r2 = (nt < 2) ? -c[nt + 2][2] : c[nt - 2][2];
            float r3 = (nt < 2) ? -c[nt + 2][3] : c[nt - 2][3];
            ushort4 o = {f2b(c[nt][0] * cv0 + r0 * sv0),
                         f2b(c[nt][1] * cv0 + r1 * sv0),
                         f2b(c[nt][2] * cv1 + r2 * sv1),
                         f2b(c[nt][3] * cv1 + r3 * sv1)};
            *(ushort4*)&drow[nt * 16] = o;
        }
    }
}

// ---------------------------------------------------------------------------
// Kernel 2: logits[z][m][n] = dot(q[z][m], k[z][n]) / 8, pad + causal mask.
// OPERAND-SWAPPED: acc[nt][mt] = mfma(K_frag, Q_frag) so output row index is
// n -> each lane holds 4 CONSECUTIVE n (m = mt*16+lr fixed) -> float4 stores
// (was 64 scalar dword stores/lane) + float4 mask loads. Nontemporal stores:
// out is a 302 MB stream, keep L2 for q/k tile reuse.
// ---------------------------------------------------------------------------
#define LDA2 72  // 64 + 8 pad; row stride 144 B, 16B-aligned
__global__ __launch_bounds__(256) void logits_mfma(
    const unsigned short* __restrict__ q_ws,
    const unsigned short* __restrict__ k_ws,
    const float* __restrict__ mask,  // [B][S]
    float* __restrict__ out) {       // [B*E][S][S]
    __shared__ unsigned short Qs[128 * LDA2];
    __shared__ unsigned short Ks[128 * LDA2];

    const int t = threadIdx.x;
    const int lane = t & 63, wave = t >> 6;
    const int quad = lane >> 4, lr = lane & 15;
    const int wm = wave >> 1, wn = wave & 1;
    const int n0 = blockIdx.x * 128;
    const int m0 = blockIdx.y * 128;
    const int z = blockIdx.z;        // b*E + e
    const int b_idx = z / EE;

    const uint4* qsrc = (const uint4*)(q_ws + ((size_t)z * SS + m0) * DD);
    const uint4* ksrc = (const uint4*)(k_ws + ((size_t)z * SS + n0) * DD);
#pragma unroll
    for (int i = 0; i < 4; ++i) {
        int idx = t + i * 256;       // 1024 16B chunks per 128x64 bf16 tile
        int row = idx >> 3, c8 = (idx & 7) * 8;
        uint4 qv = qsrc[idx];
        uint4 kv = ksrc[idx];
        *(uint4*)&Qs[row * LDA2 + c8] = qv;
        *(uint4*)&Ks[row * LDA2 + c8] = kv;
    }
    __syncthreads();

    f32x4 acc[4][4] = {};  // [nt][mt]
#pragma unroll
    for (int ks = 0; ks < DD; ks += 32) {
        bf16x8 af[4], bf[4];
#pragma unroll
        for (int nt = 0; nt < 4; ++nt)
            af[nt] = *(const bf16x8*)&Ks[(wn * 64 + nt * 16 + lr) * LDA2 + ks + quad * 8];
#pragma unroll
        for (int mt = 0; mt < 4; ++mt)
            bf[mt] = *(const bf16x8*)&Qs[(wm * 64 + mt * 16 + lr) * LDA2 + ks + quad * 8];
#pragma unroll
        for (int nt = 0; nt < 4; ++nt)
#pragma unroll
            for (int mt = 0; mt < 4; ++mt)
                acc[nt][mt] = __builtin_amdgcn_mfma_f32_16x16x32_bf16(
                    af[nt], bf[mt], acc[nt][mt], 0, 0, 0);
    }

    const int nb0 = n0 + wn * 64;
    float4 pv[4];
#pragma unroll
    for (int nt = 0; nt < 4; ++nt)
        pv[nt] = *(const float4*)&mask[b_idx * SS + nb0 + nt * 16 + quad * 4];

    float* outz = out + (size_t)z * SS * SS;
#pragma unroll
    for (int mt = 0; mt < 4; ++mt) {
        const int m = m0 + wm * 64 + mt * 16 + lr;
        float* rowp = &outz[(size_t)m * SS];
#pragma unroll
        for (int nt = 0; nt < 4; ++nt) {
            const int nb = nb0 + nt * 16 + quad * 4;
            f32x4 v;
#pragma unroll
            for (int reg = 0; reg < 4; ++reg) {
                const float p = (&pv[nt].x)[reg];
                float x = acc[nt][mt][reg] * 0.125f;
                x = x * p - (1.0f - p) * 10000.0f;
                if (nb + reg < m) x -= 10000.0f;
                v[reg] = x;
            }
            __builtin_nontemporal_store(v, (f32x4*)(rowp + nb));
        }
    }
}

extern "C" void kernel_launch(void* const* d_in, const int* in_sizes, int n_in,
                              void* d_out, int out_size, void* d_ws, size_t ws_size,
                              hipStream_t stream) {
    const float* lhs  = (const float*)d_in[0];  // [8][1024][768]
    const float* mask = (const float*)d_in[1];  // [8][1024]
    const float* W    = (const float*)d_in[2];  // [1152][768]
    const float* bias = (const float*)d_in[3];  // [1152]
    float* out = (float*)d_out;                 // [8][9][1024][1024]

    unsigned short* q_ws = (unsigned short*)d_ws;
    unsigned short* k_ws = q_ws + (size_t)BB * EE * SS * DD;   // 4,718,592 each
    unsigned short* Abf  = k_ws + (size_t)BB * EE * SS * DD;   // [8192][768] bf16
    unsigned short* Wbf  = Abf + (size_t)BB * SS * HH;         // [1152][768] bf16

    to_bf16<<<(BB * SS * HH) / 4 / 256, 256, 0, stream>>>(lhs, Abf, (BB * SS * HH) / 4);
    to_bf16<<<(NCOL * HH) / 4 / 256, 256, 0, stream>>>(W, Wbf, (NCOL * HH) / 4);

    dim3 g1(NCOL / 128, (BB * SS) / 128);  // 9 x 64
    dense_rope_mfma<<<g1, 256, 0, stream>>>(Abf, Wbf, bias, q_ws, k_ws);

    dim3 g2(SS / 128, SS / 128, BB * EE);  // 8 x 8 x 72
    logits_mfma<<<g2, 256, 0, stream>>>(q_ws, k_ws, mask, out);
}

// Round 3
// 383.028 us; speedup vs baseline: 1.0132x; 1.0132x over previous
//
#include <hip/hip_runtime.h>

#define BB 8
#define SS 1024
#define HH 768
#define EE 9
#define DD 64
#define NCOL (EE * 2 * DD)  // 1152

typedef __bf16 bf16x8 __attribute__((ext_vector_type(8)));
typedef float f32x4 __attribute__((ext_vector_type(4)));

__device__ __forceinline__ unsigned short f2b(float f) {
    unsigned int x = __float_as_uint(f);
    unsigned int r = (x + 0x7fffu + ((x >> 16) & 1u)) >> 16;
    return (unsigned short)r;
}

__device__ __forceinline__ void gload_lds16(const void* g, void* l) {
    __builtin_amdgcn_global_load_lds(
        (const __attribute__((address_space(1))) void*)g,
        (__attribute__((address_space(3))) void*)l, 16, 0, 0);
}

// ---------------------------------------------------------------------------
// Kernel 0: f32 -> bf16 (RNE) for both A and W in one launch.
// ---------------------------------------------------------------------------
__global__ __launch_bounds__(256) void to_bf16_2(
    const float* __restrict__ a, int n4a,
    const float* __restrict__ w, int n4w,
    unsigned short* __restrict__ oa,
    unsigned short* __restrict__ ow) {
    int i = blockIdx.x * 256 + threadIdx.x;
    const float* src;
    unsigned short* dst;
    int j;
    if (i < n4a) {
        src = a; dst = oa; j = i;
    } else {
        j = i - n4a;
        if (j >= n4w) return;
        src = w; dst = ow;
    }
    float4 v = ((const float4*)src)[j];
    ushort4 o = {f2b(v.x), f2b(v.y), f2b(v.z), f2b(v.w)};
    ((ushort4*)dst)[j] = o;
}

// ---------------------------------------------------------------------------
// Kernel 1: C = A @ W^T + bias, RoPE, write q/k bf16 to ws [b*E+e][s][d].
// m97 staging (global_load_lds w=16, linear LDS, BK=32). Operand-swapped
// MFMA: acc[nt][st] = mfma(W_frag, A_frag) so each lane holds 4 consecutive
// d per fragment: d = nt*16 + quad*4 + reg, s = st*16 + lr.
// -> ushort4 stores, float4 bias loads, sincos count halved (reg-pairs
// share a RoPE half-index). Rotate-half partner (d +/- 32) = nt +/- 2.
// ---------------------------------------------------------------------------
__global__ __launch_bounds__(256) void dense_rope_mfma(
    const unsigned short* __restrict__ Abf,  // [8192][768] bf16
    const unsigned short* __restrict__ Wbf,  // [1152][768] bf16
    const float* __restrict__ bias,          // [1152]
    unsigned short* __restrict__ q_ws,
    unsigned short* __restrict__ k_ws) {
    __shared__ unsigned short As[128 * 32];  // linear: gload_lds needs it
    __shared__ unsigned short Bs[128 * 32];

    const int t = threadIdx.x;
    const int lane = t & 63, wave = t >> 6;
    const int quad = lane >> 4, lr = lane & 15;
    const int wm = wave >> 1, wn = wave & 1;
    const int j0 = blockIdx.x * 128;  // x-major over N: consecutive blocks reuse A in L2
    const int m0 = blockIdx.y * 128;

    f32x4 acc[4][4] = {};  // [nt][st]

    // Staging: 128x32 bf16 tile = 8 KB = 512 x 16B chunks.
    const int srow = wave * 16 + (lane >> 2);   // + i*64
    const int sc8 = (lane & 3) * 8;

    for (int kt = 0; kt < HH / 32; ++kt) {
        const int k0 = kt * 32;
        __syncthreads();  // previous tile's LDS fully consumed
#pragma unroll
        for (int i = 0; i < 2; ++i) {
            const int row = i * 64 + srow;
            const int lb = i * 2048 + wave * 512;  // ushort offset of chunk base
            gload_lds16(&Abf[(size_t)(m0 + row) * HH + k0 + sc8], &As[lb]);
            gload_lds16(&Wbf[(size_t)(j0 + row) * HH + k0 + sc8], &Bs[lb]);
        }
        __syncthreads();  // drains vmcnt(0): staged tile visible

        bf16x8 af[4], bf[4];
#pragma unroll
        for (int nt = 0; nt < 4; ++nt)
            af[nt] = *(const bf16x8*)&Bs[(wn * 64 + nt * 16 + lr) * 32 + quad * 8];
#pragma unroll
        for (int st = 0; st < 4; ++st)
            bf[st] = *(const bf16x8*)&As[(wm * 64 + st * 16 + lr) * 32 + quad * 8];
#pragma unroll
        for (int nt = 0; nt < 4; ++nt)
#pragma unroll
            for (int st = 0; st < 4; ++st)
                acc[nt][st] = __builtin_amdgcn_mfma_f32_16x16x32_bf16(
                    af[nt], bf[st], acc[nt][st], 0, 0, 0);
    }

    // Epilogue: bias + RoPE entirely in registers, vectorized stores.
    const int gcol0 = j0 + wn * 64;       // aligned 64-col group
    const int g = gcol0 >> 6;
    const int e = g >> 1;
    unsigned short* dst = (g & 1) ? k_ws : q_ws;
    const int b_idx = m0 >> 10;           // 128 | 1024, uniform per block
    const size_t zbase = (size_t)(b_idx * EE + e) * SS;
    const float L2C = 0.4152410118609203f;  // log2(10000)/32

    float4 bb[4];
    float iv0[4], iv1[4];
#pragma unroll
    for (int nt = 0; nt < 4; ++nt) {
        bb[nt] = *(const float4*)&bias[gcol0 + nt * 16 + quad * 4];
        const int h0 = nt * 8 + quad * 2;   // = d>>1 for reg 0,1; h0+1 for reg 2,3
        iv0[nt] = exp2f(-(float)h0 * L2C);
        iv1[nt] = exp2f(-(float)(h0 + 1) * L2C);
    }
    const int s0 = (m0 & (SS - 1)) + wm * 64;
#pragma unroll
    for (int st = 0; st < 4; ++st) {
        const int s = s0 + st * 16 + lr;
        const float sf = (float)s;
        float c[4][4];
#pragma unroll
        for (int nt = 0; nt < 4; ++nt) {
            c[nt][0] = acc[nt][st][0] + bb[nt].x;
            c[nt][1] = acc[nt][st][1] + bb[nt].y;
            c[nt][2] = acc[nt][st][2] + bb[nt].z;
            c[nt][3] = acc[nt][st][3] + bb[nt].w;
        }
        unsigned short* drow = &dst[(zbase + s) * DD + quad * 4];
#pragma unroll
        for (int nt = 0; nt < 4; ++nt) {
            float sv0, cv0, sv1, cv1;
            __sincosf(sf * iv0[nt], &sv0, &cv0);
            __sincosf(sf * iv1[nt], &sv1, &cv1);
            float r0 = (nt < 2) ? -c[nt + 2][0] : c[nt - 2][0];
            float r1 = (nt < 2) ? -c[nt + 2][1] : c[nt - 2][1];
            float r2 = (nt < 2) ? -c[nt + 2][2] : c[nt - 2][2];
            float r3 = (nt < 2) ? -c[nt + 2][3] : c[nt - 2][3];
            ushort4 o = {f2b(c[nt][0] * cv0 + r0 * sv0),
                         f2b(c[nt][1] * cv0 + r1 * sv0),
                         f2b(c[nt][2] * cv1 + r2 * sv1),
                         f2b(c[nt][3] * cv1 + r3 * sv1)};
            *(ushort4*)&drow[nt * 16] = o;
        }
    }
}

// ---------------------------------------------------------------------------
// Kernel 2: logits[z][m][n] = dot(q[z][m], k[z][n]) / 8, pad + causal mask.
// NO LDS: because D=64, each lane's MFMA fragment is one contiguous 16B
// chunk of the global [z][s][d] layout -> direct global_load_dwordx4
// fragment loads (64B row-segments per wave, L2-hit on re-reads; q/k
// working set is 256 KB per z). Removes staging VALU, LDS traffic, and
// both barriers. Operand-swapped: acc[nt][mt] = mfma(K,Q) -> lane holds 4
// consecutive n -> float4 stores (plain, cached: nt-store regressed r2).
// ---------------------------------------------------------------------------
__global__ __launch_bounds__(256) void logits_mfma(
    const unsigned short* __restrict__ q_ws,
    const unsigned short* __restrict__ k_ws,
    const float* __restrict__ mask,  // [B][S]
    float* __restrict__ out) {       // [B*E][S][S]
    const int t = threadIdx.x;
    const int lane = t & 63, wave = t >> 6;
    const int quad = lane >> 4, lr = lane & 15;
    const int wm = wave >> 1, wn = wave & 1;
    const int n0 = blockIdx.x * 128;
    const int m0 = blockIdx.y * 128;
    const int z = blockIdx.z;        // b*E + e
    const int b_idx = z / EE;

    // Per-lane fragment bases: row = (tile row) + lr, col = quad*8 (+ks).
    const unsigned short* kb =
        k_ws + ((size_t)z * SS + n0 + wn * 64 + lr) * DD + quad * 8;
    const unsigned short* qb =
        q_ws + ((size_t)z * SS + m0 + wm * 64 + lr) * DD + quad * 8;

    bf16x8 af[2][4], bf[2][4];  // [ks][tile]
#pragma unroll
    for (int x = 0; x < 4; ++x) {
        af[0][x] = *(const bf16x8*)&kb[(size_t)(x * 16) * DD];
        af[1][x] = *(const bf16x8*)&kb[(size_t)(x * 16) * DD + 32];
        bf[0][x] = *(const bf16x8*)&qb[(size_t)(x * 16) * DD];
        bf[1][x] = *(const bf16x8*)&qb[(size_t)(x * 16) * DD + 32];
    }

    f32x4 acc[4][4] = {};  // [nt][mt]
#pragma unroll
    for (int ks = 0; ks < 2; ++ks)
#pragma unroll
        for (int nt = 0; nt < 4; ++nt)
#pragma unroll
            for (int mt = 0; mt < 4; ++mt)
                acc[nt][mt] = __builtin_amdgcn_mfma_f32_16x16x32_bf16(
                    af[ks][nt], bf[ks][mt], acc[nt][mt], 0, 0, 0);

    const int nb0 = n0 + wn * 64;
    float4 pv[4];
#pragma unroll
    for (int nt = 0; nt < 4; ++nt)
        pv[nt] = *(const float4*)&mask[b_idx * SS + nb0 + nt * 16 + quad * 4];

    float* outz = out + (size_t)z * SS * SS;
#pragma unroll
    for (int mt = 0; mt < 4; ++mt) {
        const int m = m0 + wm * 64 + mt * 16 + lr;
        float* rowp = &outz[(size_t)m * SS];
#pragma unroll
        for (int nt = 0; nt < 4; ++nt) {
            const int nb = nb0 + nt * 16 + quad * 4;
            f32x4 v;
#pragma unroll
            for (int reg = 0; reg < 4; ++reg) {
                const float p = (&pv[nt].x)[reg];
                float x = acc[nt][mt][reg] * 0.125f;
                x = x * p - (1.0f - p) * 10000.0f;
                if (nb + reg < m) x -= 10000.0f;
                v[reg] = x;
            }
            *(f32x4*)(rowp + nb) = v;
        }
    }
}

extern "C" void kernel_launch(void* const* d_in, const int* in_sizes, int n_in,
                              void* d_out, int out_size, void* d_ws, size_t ws_size,
                              hipStream_t stream) {
    const float* lhs  = (const float*)d_in[0];  // [8][1024][768]
    const float* mask = (const float*)d_in[1];  // [8][1024]
    const float* W    = (const float*)d_in[2];  // [1152][768]
    const float* bias = (const float*)d_in[3];  // [1152]
    float* out = (float*)d_out;                 // [8][9][1024][1024]

    unsigned short* q_ws = (unsigned short*)d_ws;
    unsigned short* k_ws = q_ws + (size_t)BB * EE * SS * DD;   // 4,718,592 each
    unsigned short* Abf  = k_ws + (size_t)BB * EE * SS * DD;   // [8192][768] bf16
    unsigned short* Wbf  = Abf + (size_t)BB * SS * HH;         // [1152][768] bf16

    const int n4a = (BB * SS * HH) / 4;   // 1,572,864
    const int n4w = (NCOL * HH) / 4;      // 221,184
    const int nconv = (n4a + n4w + 255) / 256;
    to_bf16_2<<<nconv, 256, 0, stream>>>(lhs, n4a, W, n4w, Abf, Wbf);

    dim3 g1(NCOL / 128, (BB * SS) / 128);  // 9 x 64
    dense_rope_mfma<<<g1, 256, 0, stream>>>(Abf, Wbf, bias, q_ws, k_ws);

    dim3 g2(SS / 128, SS / 128, BB * EE);  // 8 x 8 x 72
    logits_mfma<<<g2, 256, 0, stream>>>(q_ws, k_ws, mask, out);
}

// Round 4
// 368.485 us; speedup vs baseline: 1.0532x; 1.0395x over previous
//
#include <hip/hip_runtime.h>

#define BB 8
#define SS 1024
#define HH 768
#define EE 9
#define DD 64
#define NCOL (EE * 2 * DD)  // 1152

typedef __bf16 bf16x8 __attribute__((ext_vector_type(8)));
typedef float f32x4 __attribute__((ext_vector_type(4)));

__device__ __forceinline__ unsigned short f2b(float f) {
    unsigned int x = __float_as_uint(f);
    unsigned int r = (x + 0x7fffu + ((x >> 16) & 1u)) >> 16;
    return (unsigned short)r;
}

__device__ __forceinline__ void gload_lds16(const void* g, void* l) {
    __builtin_amdgcn_global_load_lds(
        (const __attribute__((address_space(1))) void*)g,
        (__attribute__((address_space(3))) void*)l, 16, 0, 0);
}

// ---------------------------------------------------------------------------
// Kernel 0: f32 -> bf16 (RNE) for both A and W in one launch.
// ---------------------------------------------------------------------------
__global__ __launch_bounds__(256) void to_bf16_2(
    const float* __restrict__ a, int n4a,
    const float* __restrict__ w, int n4w,
    unsigned short* __restrict__ oa,
    unsigned short* __restrict__ ow) {
    int i = blockIdx.x * 256 + threadIdx.x;
    const float* src;
    unsigned short* dst;
    int j;
    if (i < n4a) {
        src = a; dst = oa; j = i;
    } else {
        j = i - n4a;
        if (j >= n4w) return;
        src = w; dst = ow;
    }
    float4 v = ((const float4*)src)[j];
    ushort4 o = {f2b(v.x), f2b(v.y), f2b(v.z), f2b(v.w)};
    ((ushort4*)dst)[j] = o;
}

// ---------------------------------------------------------------------------
// Kernel 1: C = A @ W^T + bias, RoPE, write q/k bf16 to ws [b*E+e][s][d].
// m97 staging (global_load_lds w=16, linear LDS, BK=32). Operand-swapped
// MFMA: acc[nt][st] = mfma(W_frag, A_frag) so each lane holds 4 consecutive
// d per fragment: d = nt*16 + quad*4 + reg, s = st*16 + lr.
// -> ushort4 stores, float4 bias loads, sincos count halved (reg-pairs
// share a RoPE half-index). Rotate-half partner (d +/- 32) = nt +/- 2.
// ---------------------------------------------------------------------------
__global__ __launch_bounds__(256) void dense_rope_mfma(
    const unsigned short* __restrict__ Abf,  // [8192][768] bf16
    const unsigned short* __restrict__ Wbf,  // [1152][768] bf16
    const float* __restrict__ bias,          // [1152]
    unsigned short* __restrict__ q_ws,
    unsigned short* __restrict__ k_ws) {
    __shared__ unsigned short As[128 * 32];  // linear: gload_lds needs it
    __shared__ unsigned short Bs[128 * 32];

    const int t = threadIdx.x;
    const int lane = t & 63, wave = t >> 6;
    const int quad = lane >> 4, lr = lane & 15;
    const int wm = wave >> 1, wn = wave & 1;
    const int j0 = blockIdx.x * 128;  // x-major over N: consecutive blocks reuse A in L2
    const int m0 = blockIdx.y * 128;

    f32x4 acc[4][4] = {};  // [nt][st]

    // Staging: 128x32 bf16 tile = 8 KB = 512 x 16B chunks.
    const int srow = wave * 16 + (lane >> 2);   // + i*64
    const int sc8 = (lane & 3) * 8;

    for (int kt = 0; kt < HH / 32; ++kt) {
        const int k0 = kt * 32;
        __syncthreads();  // previous tile's LDS fully consumed
#pragma unroll
        for (int i = 0; i < 2; ++i) {
            const int row = i * 64 + srow;
            const int lb = i * 2048 + wave * 512;  // ushort offset of chunk base
            gload_lds16(&Abf[(size_t)(m0 + row) * HH + k0 + sc8], &As[lb]);
            gload_lds16(&Wbf[(size_t)(j0 + row) * HH + k0 + sc8], &Bs[lb]);
        }
        __syncthreads();  // drains vmcnt(0): staged tile visible

        bf16x8 af[4], bf[4];
#pragma unroll
        for (int nt = 0; nt < 4; ++nt)
            af[nt] = *(const bf16x8*)&Bs[(wn * 64 + nt * 16 + lr) * 32 + quad * 8];
#pragma unroll
        for (int st = 0; st < 4; ++st)
            bf[st] = *(const bf16x8*)&As[(wm * 64 + st * 16 + lr) * 32 + quad * 8];
#pragma unroll
        for (int nt = 0; nt < 4; ++nt)
#pragma unroll
            for (int st = 0; st < 4; ++st)
                acc[nt][st] = __builtin_amdgcn_mfma_f32_16x16x32_bf16(
                    af[nt], bf[st], acc[nt][st], 0, 0, 0);
    }

    // Epilogue: bias + RoPE entirely in registers, vectorized stores.
    const int gcol0 = j0 + wn * 64;       // aligned 64-col group
    const int g = gcol0 >> 6;
    const int e = g >> 1;
    unsigned short* dst = (g & 1) ? k_ws : q_ws;
    const int b_idx = m0 >> 10;           // 128 | 1024, uniform per block
    const size_t zbase = (size_t)(b_idx * EE + e) * SS;
    const float L2C = 0.4152410118609203f;  // log2(10000)/32

    float4 bb[4];
    float iv0[4], iv1[4];
#pragma unroll
    for (int nt = 0; nt < 4; ++nt) {
        bb[nt] = *(const float4*)&bias[gcol0 + nt * 16 + quad * 4];
        const int h0 = nt * 8 + quad * 2;   // = d>>1 for reg 0,1; h0+1 for reg 2,3
        iv0[nt] = exp2f(-(float)h0 * L2C);
        iv1[nt] = exp2f(-(float)(h0 + 1) * L2C);
    }
    const int s0 = (m0 & (SS - 1)) + wm * 64;
#pragma unroll
    for (int st = 0; st < 4; ++st) {
        const int s = s0 + st * 16 + lr;
        const float sf = (float)s;
        float c[4][4];
#pragma unroll
        for (int nt = 0; nt < 4; ++nt) {
            c[nt][0] = acc[nt][st][0] + bb[nt].x;
            c[nt][1] = acc[nt][st][1] + bb[nt].y;
            c[nt][2] = acc[nt][st][2] + bb[nt].z;
            c[nt][3] = acc[nt][st][3] + bb[nt].w;
        }
        unsigned short* drow = &dst[(zbase + s) * DD + quad * 4];
#pragma unroll
        for (int nt = 0; nt < 4; ++nt) {
            float sv0, cv0, sv1, cv1;
            __sincosf(sf * iv0[nt], &sv0, &cv0);
            __sincosf(sf * iv1[nt], &sv1, &cv1);
            float r0 = (nt < 2) ? -c[nt + 2][0] : c[nt - 2][0];
            float r1 = (nt < 2) ? -c[nt + 2][1] : c[nt - 2][1];
            float r2 = (nt < 2) ? -c[nt + 2][2] : c[nt - 2][2];
            float r3 = (nt < 2) ? -c[nt + 2][3] : c[nt - 2][3];
            ushort4 o = {f2b(c[nt][0] * cv0 + r0 * sv0),
                         f2b(c[nt][1] * cv0 + r1 * sv0),
                         f2b(c[nt][2] * cv1 + r2 * sv1),
                         f2b(c[nt][3] * cv1 + r3 * sv1)};
            *(ushort4*)&drow[nt * 16] = o;
        }
    }
}

// ---------------------------------------------------------------------------
// Kernel 2: logits[z][m][n] = dot(q[z][m], k[z][n]) / 8, pad + causal mask.
// REVERTED VERBATIM to the round-1 (365 us) structure: 128x128 tile per
// block, LDS-staged (coalesced uint4 loads), K=64 staged once, unswapped
// mfma(Q,K), scalar dword stores. The r2/r3 rework (operand swap, no-LDS
// fragment loads, vector/nt stores) regressed +18-23 us net and is
// abandoned pending per-change isolation.
// ---------------------------------------------------------------------------
#define LDA2 72  // 64 + 8 pad; row stride 144 B, 16B-aligned
__global__ __launch_bounds__(256) void logits_mfma(
    const unsigned short* __restrict__ q_ws,
    const unsigned short* __restrict__ k_ws,
    const float* __restrict__ mask,  // [B][S]
    float* __restrict__ out) {       // [B*E][S][S]
    __shared__ unsigned short Qs[128 * LDA2];
    __shared__ unsigned short Ks[128 * LDA2];

    const int t = threadIdx.x;
    const int lane = t & 63, wave = t >> 6;
    const int quad = lane >> 4, lr = lane & 15;
    const int wm = wave >> 1, wn = wave & 1;
    const int n0 = blockIdx.x * 128;
    const int m0 = blockIdx.y * 128;
    const int z = blockIdx.z;        // b*E + e
    const int b_idx = z / EE;

    const uint4* qsrc = (const uint4*)(q_ws + ((size_t)z * SS + m0) * DD);
    const uint4* ksrc = (const uint4*)(k_ws + ((size_t)z * SS + n0) * DD);
#pragma unroll
    for (int i = 0; i < 4; ++i) {
        int idx = t + i * 256;       // 1024 16B chunks per 128x64 bf16 tile
        int row = idx >> 3, c8 = (idx & 7) * 8;
        uint4 qv = qsrc[idx];
        uint4 kv = ksrc[idx];
        *(uint4*)&Qs[row * LDA2 + c8] = qv;
        *(uint4*)&Ks[row * LDA2 + c8] = kv;
    }
    __syncthreads();

    f32x4 acc[4][4] = {};
#pragma unroll
    for (int ks = 0; ks < DD; ks += 32) {
        bf16x8 af[4], bf[4];
#pragma unroll
        for (int mt = 0; mt < 4; ++mt)
            af[mt] = *(const bf16x8*)&Qs[(wm * 64 + mt * 16 + lr) * LDA2 + ks + quad * 8];
#pragma unroll
        for (int nt = 0; nt < 4; ++nt)
            bf[nt] = *(const bf16x8*)&Ks[(wn * 64 + nt * 16 + lr) * LDA2 + ks + quad * 8];
#pragma unroll
        for (int mt = 0; mt < 4; ++mt)
#pragma unroll
            for (int nt = 0; nt < 4; ++nt)
                acc[mt][nt] = __builtin_amdgcn_mfma_f32_16x16x32_bf16(
                    af[mt], bf[nt], acc[mt][nt], 0, 0, 0);
    }

    float p[4];
#pragma unroll
    for (int nt = 0; nt < 4; ++nt)
        p[nt] = mask[b_idx * SS + n0 + wn * 64 + nt * 16 + lr];

    float* outz = out + (size_t)z * SS * SS;
#pragma unroll
    for (int mt = 0; mt < 4; ++mt) {
#pragma unroll
        for (int reg = 0; reg < 4; ++reg) {
            const int m = m0 + wm * 64 + mt * 16 + quad * 4 + reg;
#pragma unroll
            for (int nt = 0; nt < 4; ++nt) {
                const int n = n0 + wn * 64 + nt * 16 + lr;
                float v = acc[mt][nt][reg] * 0.125f;
                v = v * p[nt] - (1.0f - p[nt]) * 10000.0f;
                if (n < m) v -= 10000.0f;
                outz[(size_t)m * SS + n] = v;
            }
        }
    }
}

extern "C" void kernel_launch(void* const* d_in, const int* in_sizes, int n_in,
                              void* d_out, int out_size, void* d_ws, size_t ws_size,
                              hipStream_t stream) {
    const float* lhs  = (const float*)d_in[0];  // [8][1024][768]
    const float* mask = (const float*)d_in[1];  // [8][1024]
    const float* W    = (const float*)d_in[2];  // [1152][768]
    const float* bias = (const float*)d_in[3];  // [1152]
    float* out = (float*)d_out;                 // [8][9][1024][1024]

    unsigned short* q_ws = (unsigned short*)d_ws;
    unsigned short* k_ws = q_ws + (size_t)BB * EE * SS * DD;   // 4,718,592 each
    unsigned short* Abf  = k_ws + (size_t)BB * EE * SS * DD;   // [8192][768] bf16
    unsigned short* Wbf  = Abf + (size_t)BB * SS * HH;         // [1152][768] bf16

    const int n4a = (BB * SS * HH) / 4;   // 1,572,864
    const int n4w = (NCOL * HH) / 4;      // 221,184
    const int nconv = (n4a + n4w + 255) / 256;
    to_bf16_2<<<nconv, 256, 0, stream>>>(lhs, n4a, W, n4w, Abf, Wbf);

    dim3 g1(NCOL / 128, (BB * SS) / 128);  // 9 x 64
    dense_rope_mfma<<<g1, 256, 0, stream>>>(Abf, Wbf, bias, q_ws, k_ws);

    dim3 g2(SS / 128, SS / 128, BB * EE);  // 8 x 8 x 72
    logits_mfma<<<g2, 256, 0, stream>>>(q_ws, k_ws, mask, out);
}

// Round 7
// 356.784 us; speedup vs baseline: 1.0877x; 1.0328x over previous
//
#include <hip/hip_runtime.h>

#define BB 8
#define SS 1024
#define HH 768
#define EE 9
#define DD 64
#define NCOL (EE * 2 * DD)  // 1152

typedef __bf16 bf16x8 __attribute__((ext_vector_type(8)));
typedef float f32x4 __attribute__((ext_vector_type(4)));

__device__ __forceinline__ unsigned short f2b(float f) {
    unsigned int x = __float_as_uint(f);
    unsigned int r = (x + 0x7fffu + ((x >> 16) & 1u)) >> 16;
    return (unsigned short)r;
}

__device__ __forceinline__ void gload_lds16(const void* g, void* l) {
    __builtin_amdgcn_global_load_lds(
        (const __attribute__((address_space(1))) void*)g,
        (__attribute__((address_space(3))) void*)l, 16, 0, 0);
}

// ---------------------------------------------------------------------------
// Kernel 0: f32 -> bf16 (RNE) for both A and W in one launch.
// ---------------------------------------------------------------------------
__global__ __launch_bounds__(256) void to_bf16_2(
    const float* __restrict__ a, int n4a,
    const float* __restrict__ w, int n4w,
    unsigned short* __restrict__ oa,
    unsigned short* __restrict__ ow) {
    int i = blockIdx.x * 256 + threadIdx.x;
    const float* src;
    unsigned short* dst;
    int j;
    if (i < n4a) {
        src = a; dst = oa; j = i;
    } else {
        j = i - n4a;
        if (j >= n4w) return;
        src = w; dst = ow;
    }
    float4 v = ((const float4*)src)[j];
    ushort4 o = {f2b(v.x), f2b(v.y), f2b(v.z), f2b(v.w)};
    ((ushort4*)dst)[j] = o;
}

// ---------------------------------------------------------------------------
// Kernel 1: C = A @ W^T + bias, RoPE, write q/k bf16 to ws [b*E+e][s][d].
// m97 staging (global_load_lds w=16, linear LDS, BK=32). Operand-swapped
// MFMA: acc[nt][st] = mfma(W_frag, A_frag) so each lane holds 4 consecutive
// d per fragment: d = nt*16 + quad*4 + reg, s = st*16 + lr.
// T1 XCD swizzle: round-robin dispatch (xcd = linear_id % 8) would spread
// the 9 blocks sharing one A row-slice across 8 XCD L2s (A pulled ~8x from
// L3). Chunked remap: XCD k owns y-groups [8k, 8k+8), x fastest -> A-slice
// read once per XCD, W (1.7 MB) L2-resident. Bijection: l = w*8 + xcd,
// w = (y%8)*9 + x.
// ---------------------------------------------------------------------------
__global__ __launch_bounds__(256) void dense_rope_mfma(
    const unsigned short* __restrict__ Abf,  // [8192][768] bf16
    const unsigned short* __restrict__ Wbf,  // [1152][768] bf16
    const float* __restrict__ bias,          // [1152]
    unsigned short* __restrict__ q_ws,
    unsigned short* __restrict__ k_ws) {
    __shared__ unsigned short As[128 * 32];  // linear: gload_lds needs it
    __shared__ unsigned short Bs[128 * 32];

    const int t = threadIdx.x;
    const int lane = t & 63, wave = t >> 6;
    const int quad = lane >> 4, lr = lane & 15;
    const int wm = wave >> 1, wn = wave & 1;

    // XCD-chunked block remap (bijective on 576 = 8 xcd * 8 y * 9 x).
    const int l = blockIdx.y * 9 + blockIdx.x;  // dispatch-linear id
    const int xcd = l & 7;
    const int w = l >> 3;                        // [0,72)
    const int yl = w / 9;                        // [0,8)
    const int xg = w - yl * 9;                   // [0,9)
    const int j0 = xg * 128;
    const int m0 = (xcd * 8 + yl) * 128;

    f32x4 acc[4][4] = {};  // [nt][st]

    // Staging: 128x32 bf16 tile = 8 KB = 512 x 16B chunks.
    const int srow = wave * 16 + (lane >> 2);   // + i*64
    const int sc8 = (lane & 3) * 8;

    for (int kt = 0; kt < HH / 32; ++kt) {
        const int k0 = kt * 32;
        __syncthreads();  // previous tile's LDS fully consumed
#pragma unroll
        for (int i = 0; i < 2; ++i) {
            const int row = i * 64 + srow;
            const int lb = i * 2048 + wave * 512;  // ushort offset of chunk base
            gload_lds16(&Abf[(size_t)(m0 + row) * HH + k0 + sc8], &As[lb]);
            gload_lds16(&Wbf[(size_t)(j0 + row) * HH + k0 + sc8], &Bs[lb]);
        }
        __syncthreads();  // drains vmcnt(0): staged tile visible

        bf16x8 af[4], bf[4];
#pragma unroll
        for (int nt = 0; nt < 4; ++nt)
            af[nt] = *(const bf16x8*)&Bs[(wn * 64 + nt * 16 + lr) * 32 + quad * 8];
#pragma unroll
        for (int st = 0; st < 4; ++st)
            bf[st] = *(const bf16x8*)&As[(wm * 64 + st * 16 + lr) * 32 + quad * 8];
#pragma unroll
        for (int nt = 0; nt < 4; ++nt)
#pragma unroll
            for (int st = 0; st < 4; ++st)
                acc[nt][st] = __builtin_amdgcn_mfma_f32_16x16x32_bf16(
                    af[nt], bf[st], acc[nt][st], 0, 0, 0);
    }

    // Epilogue: bias + RoPE entirely in registers, vectorized stores.
    const int gcol0 = j0 + wn * 64;       // aligned 64-col group
    const int g = gcol0 >> 6;
    const int e = g >> 1;
    unsigned short* dst = (g & 1) ? k_ws : q_ws;
    const int b_idx = m0 >> 10;           // 128 | 1024, uniform per block
    const size_t zbase = (size_t)(b_idx * EE + e) * SS;
    const float L2C = 0.4152410118609203f;  // log2(10000)/32

    float4 bb[4];
    float iv0[4], iv1[4];
#pragma unroll
    for (int nt = 0; nt < 4; ++nt) {
        bb[nt] = *(const float4*)&bias[gcol0 + nt * 16 + quad * 4];
        const int h0 = nt * 8 + quad * 2;   // = d>>1 for reg 0,1; h0+1 for reg 2,3
        iv0[nt] = exp2f(-(float)h0 * L2C);
        iv1[nt] = exp2f(-(float)(h0 + 1) * L2C);
    }
    const int s0 = (m0 & (SS - 1)) + wm * 64;
#pragma unroll
    for (int st = 0; st < 4; ++st) {
        const int s = s0 + st * 16 + lr;
        const float sf = (float)s;
        float c[4][4];
#pragma unroll
        for (int nt = 0; nt < 4; ++nt) {
            c[nt][0] = acc[nt][st][0] + bb[nt].x;
            c[nt][1] = acc[nt][st][1] + bb[nt].y;
            c[nt][2] = acc[nt][st][2] + bb[nt].z;
            c[nt][3] = acc[nt][st][3] + bb[nt].w;
        }
        unsigned short* drow = &dst[(zbase + s) * DD + quad * 4];
#pragma unroll
        for (int nt = 0; nt < 4; ++nt) {
            float sv0, cv0, sv1, cv1;
            __sincosf(sf * iv0[nt], &sv0, &cv0);
            __sincosf(sf * iv1[nt], &sv1, &cv1);
            float r0 = (nt < 2) ? -c[nt + 2][0] : c[nt - 2][0];
            float r1 = (nt < 2) ? -c[nt + 2][1] : c[nt - 2][1];
            float r2 = (nt < 2) ? -c[nt + 2][2] : c[nt - 2][2];
            float r3 = (nt < 2) ? -c[nt + 2][3] : c[nt - 2][3];
            ushort4 o = {f2b(c[nt][0] * cv0 + r0 * sv0),
                         f2b(c[nt][1] * cv0 + r1 * sv0),
                         f2b(c[nt][2] * cv1 + r2 * sv1),
                         f2b(c[nt][3] * cv1 + r3 * sv1)};
            *(ushort4*)&drow[nt * 16] = o;
        }
    }
}

// ---------------------------------------------------------------------------
// Kernel 2: logits[z][m][n] = dot(q[z][m], k[z][n]) / 8, pad + causal mask.
// R1 structure (LDS-staged, unswapped mfma(Q,K), scalar stores) — the r2/r3
// inner-structure rework regressed and is abandoned. T1 XCD swizzle only:
// dispatch-linear id l = z*64 + y*8 + x gives xcd = x, so each XCD read the
// FULL q per z (8x q traffic from L3). Chunked remap: XCD k owns z in
// [9k, 9k+9); per-z q+k (262 KB) stays L2-resident across its 64 (m,n)
// blocks. Bijection: l = w*8 + xcd, w = (z%9)*64 + y*8 + x.
// ---------------------------------------------------------------------------
#define LDA2 72  // 64 + 8 pad; row stride 144 B, 16B-aligned
__global__ __launch_bounds__(256) void logits_mfma(
    const unsigned short* __restrict__ q_ws,
    const unsigned short* __restrict__ k_ws,
    const float* __restrict__ mask,  // [B][S]
    float* __restrict__ out) {       // [B*E][S][S]
    __shared__ unsigned short Qs[128 * LDA2];
    __shared__ unsigned short Ks[128 * LDA2];

    const int t = threadIdx.x;
    const int lane = t & 63, wave = t >> 6;
    const int quad = lane >> 4, lr = lane & 15;
    const int wm = wave >> 1, wn = wave & 1;

    // XCD-chunked block remap (bijective on 4608 = 8 xcd * 9 z * 64 mn).
    const int l = (blockIdx.z * 8 + blockIdx.y) * 8 + blockIdx.x;
    const int xcd = l & 7;
    const int w = l >> 3;            // [0,576)
    const int zl = w >> 6;           // [0,9)
    const int r = w & 63;
    const int z = xcd * 9 + zl;      // b*E + e
    const int m0 = (r >> 3) * 128;
    const int n0 = (r & 7) * 128;
    const int b_idx = z / EE;

    const uint4* qsrc = (const uint4*)(q_ws + ((size_t)z * SS + m0) * DD);
    const uint4* ksrc = (const uint4*)(k_ws + ((size_t)z * SS + n0) * DD);
#pragma unroll
    for (int i = 0; i < 4; ++i) {
        int idx = t + i * 256;       // 1024 16B chunks per 128x64 bf16 tile
        int row = idx >> 3, c8 = (idx & 7) * 8;
        uint4 qv = qsrc[idx];
        uint4 kv = ksrc[idx];
        *(uint4*)&Qs[row * LDA2 + c8] = qv;
        *(uint4*)&Ks[row * LDA2 + c8] = kv;
    }
    __syncthreads();

    f32x4 acc[4][4] = {};
#pragma unroll
    for (int ks = 0; ks < DD; ks += 32) {
        bf16x8 af[4], bf[4];
#pragma unroll
        for (int mt = 0; mt < 4; ++mt)
            af[mt] = *(const bf16x8*)&Qs[(wm * 64 + mt * 16 + lr) * LDA2 + ks + quad * 8];
#pragma unroll
        for (int nt = 0; nt < 4; ++nt)
            bf[nt] = *(const bf16x8*)&Ks[(wn * 64 + nt * 16 + lr) * LDA2 + ks + quad * 8];
#pragma unroll
        for (int mt = 0; mt < 4; ++mt)
#pragma unroll
            for (int nt = 0; nt < 4; ++nt)
                acc[mt][nt] = __builtin_amdgcn_mfma_f32_16x16x32_bf16(
                    af[mt], bf[nt], acc[mt][nt], 0, 0, 0);
    }

    float p[4];
#pragma unroll
    for (int nt = 0; nt < 4; ++nt)
        p[nt] = mask[b_idx * SS + n0 + wn * 64 + nt * 16 + lr];

    float* outz = out + (size_t)z * SS * SS;
#pragma unroll
    for (int mt = 0; mt < 4; ++mt) {
#pragma unroll
        for (int reg = 0; reg < 4; ++reg) {
            const int m = m0 + wm * 64 + mt * 16 + quad * 4 + reg;
#pragma unroll
            for (int nt = 0; nt < 4; ++nt) {
                const int n = n0 + wn * 64 + nt * 16 + lr;
                float v = acc[mt][nt][reg] * 0.125f;
                v = v * p[nt] - (1.0f - p[nt]) * 10000.0f;
                if (n < m) v -= 10000.0f;
                outz[(size_t)m * SS + n] = v;
            }
        }
    }
}

extern "C" void kernel_launch(void* const* d_in, const int* in_sizes, int n_in,
                              void* d_out, int out_size, void* d_ws, size_t ws_size,
                              hipStream_t stream) {
    const float* lhs  = (const float*)d_in[0];  // [8][1024][768]
    const float* mask = (const float*)d_in[1];  // [8][1024]
    const float* W    = (const float*)d_in[2];  // [1152][768]
    const float* bias = (const float*)d_in[3];  // [1152]
    float* out = (float*)d_out;                 // [8][9][1024][1024]

    unsigned short* q_ws = (unsigned short*)d_ws;
    unsigned short* k_ws = q_ws + (size_t)BB * EE * SS * DD;   // 4,718,592 each
    unsigned short* Abf  = k_ws + (size_t)BB * EE * SS * DD;   // [8192][768] bf16
    unsigned short* Wbf  = Abf + (size_t)BB * SS * HH;         // [1152][768] bf16

    const int n4a = (BB * SS * HH) / 4;   // 1,572,864
    const int n4w = (NCOL * HH) / 4;      // 221,184
    const int nconv = (n4a + n4w + 255) / 256;
    to_bf16_2<<<nconv, 256, 0, stream>>>(lhs, n4a, W, n4w, Abf, Wbf);

    dim3 g1(NCOL / 128, (BB * SS) / 128);  // 9 x 64
    dense_rope_mfma<<<g1, 256, 0, stream>>>(Abf, Wbf, bias, q_ws, k_ws);

    dim3 g2(SS / 128, SS / 128, BB * EE);  // 8 x 8 x 72
    logits_mfma<<<g2, 256, 0, stream>>>(q_ws, k_ws, mask, out);
}